// Round 3
// baseline (161.018 us; speedup 1.0000x reference)
//
#include <hip/hip_runtime.h>
#include <math.h>

#define E_TYPES 20
#define NBLK 2
#define NANG 7
#define CS 384
#define CH 128
#define N_TOK (8 * 2048)
#define TOK 32
#define TPB 256
#define TPB_MAIN 512
#define KC 128
#define MAX_TILES (N_TOK / TOK + E_TYPES)   // 532
#define NPREP 64

// ---- workspace: int control region ----
#define HIST_OFF 0           // 64 x 20 per-block histograms

// ---- workspace: fragment-packed split-bf16 weights (bytes) ----
// 1KB block = 64 lanes x 16B; element (n,k): lane = (n&15)|((k>>3&3)<<4), j=k&7
#define WT1_OFF (256 * 1024)                       // phase-1 concat [768x128] per e
#define WT1_SZ  (20 * 8 * 24 * 2048)               // e x nt(8) x kb(24) x (hi1KB+lo1KB)
#define WTR_OFF (WT1_OFF + WT1_SZ)                 // residual: e x m4(4) x nt(8) x kb(4)
// total end ~13.4 MB

typedef __attribute__((ext_vector_type(8))) short bfrag;
typedef __attribute__((ext_vector_type(4))) float f32x4;
typedef unsigned short (*arr136)[136];

// Raw barrier: LDS visibility only (lgkmcnt). Global prefetches stay in
// flight across it (the compiler's __syncthreads would drain vmcnt(0)).
#define BAR() do { \
    asm volatile("s_waitcnt lgkmcnt(0)" ::: "memory"); \
    __builtin_amdgcn_s_barrier(); \
    asm volatile("" ::: "memory"); \
} while (0)

__device__ __forceinline__ void split_bf16(float x, unsigned short& h, unsigned short& l) {
    unsigned int u = __float_as_uint(x);
    unsigned int hb = (u + 0x7FFFu + ((u >> 16) & 1u)) & 0xFFFF0000u;
    h = (unsigned short)(hb >> 16);
    float r = x - __uint_as_float(hb);
    unsigned int v = __float_as_uint(r);
    l = (unsigned short)((v + 0x7FFFu + ((v >> 16) & 1u)) >> 16);
}

// prep1: blocks [0,1600) convert weights to fragment-packed split-bf16;
// blocks [1600,1664) build the per-block token histogram.
__global__ void prep1(const float* __restrict__ Win, const float* __restrict__ Winit,
                      const float* __restrict__ Wb1, const float* __restrict__ Wb2,
                      const int* __restrict__ aatype, int* __restrict__ wsI,
                      unsigned short* __restrict__ wt) {
    __shared__ int lh[E_TYPES];
    int bid = blockIdx.x;
    int t = threadIdx.x;
    if (bid >= 1600) {   // histogram part
        int b2 = bid - 1600;
        if (t < E_TYPES) lh[t] = 0;
        __syncthreads();
        int idx = b2 * 256 + t;
        if (idx < N_TOK) atomicAdd(&lh[aatype[idx]], 1);
        __syncthreads();
        if (t < E_TYPES) wsI[HIST_OFF + b2 * E_TYPES + t] = lh[t];
        return;
    }
    int gid = bid * 256 + t;
    unsigned short h[8], l[8];
    if (gid < 245760) {          // phase-1 weights: 20*8*24 blocks x 64 lanes
        int lane = gid & 63;
        int bi = gid >> 6;
        int kb = bi % 24;
        int r = bi / 24;
        int nt = r & 7, e = r >> 3;
        int n = nt * 16 + (lane & 15);
        int k0 = kb * 32 + (lane >> 4) * 8;
        #pragma unroll
        for (int j = 0; j < 8; j++) {
            int k = k0 + j;
            float x = (k < CS) ? Win[((size_t)e * CS + k) * CH + n]
                               : Winit[((size_t)e * CS + (k - CS)) * CH + n];
            split_bf16(x, h[j], l[j]);
        }
        unsigned short* dst = wt + (WT1_OFF / 2) + (size_t)bi * 1024 + lane * 8;
        *(bfrag*)dst = *(bfrag*)h;
        *(bfrag*)(dst + 512) = *(bfrag*)l;
    } else {                     // residual weights: 20*4*8*4 blocks x 64 lanes
        gid -= 245760;
        int lane = gid & 63;
        int bi = gid >> 6;       // 0..2559
        int kb = bi & 3;
        int nt = (bi >> 2) & 7;
        int m4 = (bi >> 5) & 3;
        int e = bi >> 7;
        int b = m4 >> 1;
        const float* W = (m4 & 1) ? Wb2 : Wb1;
        int n = nt * 16 + (lane & 15);
        int k0 = kb * 32 + (lane >> 4) * 8;
        #pragma unroll
        for (int j = 0; j < 8; j++) {
            int k = k0 + j;
            float x = W[(((size_t)e * NBLK + b) * CH + k) * CH + n];
            split_bf16(x, h[j], l[j]);
        }
        unsigned short* dst = wt + (WTR_OFF / 2) + (size_t)bi * 1024 + lane * 8;
        *(bfrag*)dst = *(bfrag*)h;
        *(bfrag*)(dst + 512) = *(bfrag*)l;
    }
}

#define MFMA(a, b, c) __builtin_amdgcn_mfma_f32_16x16x32_bf16((a), (b), (c), 0, 0, 0)

// 8 waves; wave w owns N-tile w (16 cols), 2 M-tiles. One raw barrier per
// pipeline stage; weight fragments prefetched 2-deep across barriers
// (ks0/ks1 of stage s+1 issued mid-stage s, ks2/ks3 at stage entry);
// activations 1 chunk ahead in registers. Accumulator split into 2 chains.
__global__ __launch_bounds__(TPB_MAIN, 4)
void angle_main(const float* __restrict__ s, const float* __restrict__ si,
                const float* __restrict__ b_in, const float* __restrict__ b_init2,
                const float* __restrict__ bb1, const float* __restrict__ bb2,
                const float* __restrict__ Wout, const float* __restrict__ b_out,
                const int* __restrict__ aatype,
                const int* __restrict__ wsI, const unsigned short* __restrict__ wt,
                float* __restrict__ out)
{
    #define BUFSZ 17408
    __shared__ __align__(16) char pool[2 * BUFSZ];
    __shared__ int ptok[TOK];
    __shared__ int cntS[E_TYPES];

    arr136 AH0 = (arr136)(pool);
    arr136 AL0 = (arr136)(pool + 8704);
    arr136 AH1 = (arr136)(pool + BUFSZ);
    arr136 AL1 = (arr136)(pool + BUFSZ + 8704);
    float (*Hf)[132] = (float (*)[132])(pool);
    float (*Of)[16]  = (float (*)[16])(pool + BUFSZ);

    int t = threadIdx.x;
    int w = t >> 6, lane = t & 63;
    int lane15 = lane & 15, quad = lane >> 4;

    // XCD-chunked bijective swizzle (e-sorted tiles -> per-XCD L2 residency).
    int bid = blockIdx.x;
    const int q = MAX_TILES >> 3, r = MAX_TILES & 7;   // 66, 4
    int xcd = bid & 7, sub = bid >> 3;
    int tile = (xcd < r ? xcd * (q + 1) : r * (q + 1) + (xcd - r) * q) + sub;

    // wave0: per-type totals from the 64x20 chunk histograms
    if (w == 0 && lane < E_TYPES) {
        int c = 0;
        #pragma unroll
        for (int b = 0; b < NPREP; b++) c += wsI[HIST_OFF + b * E_TYPES + lane];
        cntS[lane] = c;
    }
    BAR();

    int pos = tile * TOK;
    int e = -1, poff_e = 0;
    {
        int accT = 0;
        #pragma unroll
        for (int ee = 0; ee < E_TYPES; ee++) {
            int pad = (cntS[ee] + TOK - 1) & ~(TOK - 1);
            if (e < 0 && pos < accT + pad) { e = ee; poff_e = accT; }
            accT += pad;
        }
        if (pos >= accT) return;     // uniform exit (all waves agree)
    }
    int pos_in = pos - poff_e;
    int n = cntS[e] - pos_in; if (n > TOK) n = TOK;

    int nc = w * 16 + lane15;
    const bfrag* wt1 = (const bfrag*)((const char*)wt + WT1_OFF);
    const bfrag* wtr = (const bfrag*)((const char*)wt + WTR_OFF);
    size_t wb = (size_t)(e * 8 + w) * 24;

    // Early issue: chunk-0 ks0/ks1 weight fragments + all bias values.
    bfrag Bd[2][4];
    {
        const bfrag* nb = wt1 + wb * 128 + lane;
        Bd[0][0] = nb[0];   Bd[0][1] = nb[128];
        Bd[0][2] = nb[64];  Bd[0][3] = nb[192];
    }
    float bv_in  = b_in[e * CH + nc] + b_init2[e * CH + nc];
    float bvb1a = bb1[(e * NBLK + 0) * CH + nc];
    float bvb1b = bb1[(e * NBLK + 1) * CH + nc];
    float bvb2a = bb2[(e * NBLK + 0) * CH + nc];
    float bvb2b = bb2[(e * NBLK + 1) * CH + nc];

    // wave0: rank-scan aatype -> ptok (overlaps other waves' prefetch)
    if (w == 0) {
        int hb = wsI[HIST_OFF + lane * E_TYPES + e];
        int inc = hb;
        #pragma unroll
        for (int d = 1; d < 64; d <<= 1) { int v = __shfl_up(inc, d); if (lane >= d) inc += v; }
        int pre = inc - hb;
        unsigned long long mle = __ballot(pre <= pos_in);
        int cb = 63 - __clzll(mle);
        int running = __shfl(pre, cb);
        int base = cb * 256;
        int lim = pos_in + n;
        while (running < lim && base < N_TOK) {
            const int4 a4 = *(const int4*)&aatype[base + lane * 4];
            int m0 = (a4.x == e), m1 = (a4.y == e), m2 = (a4.z == e), m3 = (a4.w == e);
            int c = m0 + m1 + m2 + m3;
            int incl = c;
            #pragma unroll
            for (int d = 1; d < 64; d <<= 1) { int v = __shfl_up(incl, d); if (lane >= d) incl += v; }
            int rk = running + incl - c;
            int tk = base + lane * 4;
            if (m0) { if (rk >= pos_in && rk < lim) ptok[rk - pos_in] = tk;     rk++; }
            if (m1) { if (rk >= pos_in && rk < lim) ptok[rk - pos_in] = tk + 1; rk++; }
            if (m2) { if (rk >= pos_in && rk < lim) ptok[rk - pos_in] = tk + 2; rk++; }
            if (m3) { if (rk >= pos_in && rk < lim) ptok[rk - pos_in] = tk + 3; rk++; }
            running += __shfl(incl, 63);
            base += 256;
        }
        int t0 = ptok[0];
        if (lane >= n && lane < TOK) ptok[lane] = t0;
    }
    BAR();

    // ---- phase-1 staging prologue ----
    int srow = t >> 4;
    int scol = (t & 15) * 8;
    size_t rowoff = (size_t)ptok[srow] * CS + scol;
    float4 p0 = *(const float4*)(s + rowoff);
    float4 p1 = *(const float4*)(s + rowoff + 4);
    {   // chunk 0 -> buf0
        float xv[8] = {p0.x, p0.y, p0.z, p0.w, p1.x, p1.y, p1.z, p1.w};
        unsigned short h8[8], l8[8];
        #pragma unroll
        for (int j = 0; j < 8; j++) split_bf16(fmaxf(xv[j], 0.f), h8[j], l8[j]);
        *(bfrag*)&AH0[srow][scol] = *(bfrag*)h8;
        *(bfrag*)&AL0[srow][scol] = *(bfrag*)l8;
    }
    // issue chunk-1 activation loads (fly across the barrier)
    p0 = *(const float4*)(s + rowoff + KC);
    p1 = *(const float4*)(s + rowoff + KC + 4);

    f32x4 aA0 = (f32x4){bv_in, bv_in, bv_in, bv_in};
    f32x4 aA1 = aA0;
    f32x4 aB0 = (f32x4){0.f, 0.f, 0.f, 0.f};
    f32x4 aB1 = aB0;
    BAR();

    // ---- phase 1: 6 chunks, one barrier each ----
    #pragma unroll
    for (int c = 0; c < 6; c++) {
        arr136 WAH = (c & 1) ? AH1 : AH0;
        arr136 WAL = (c & 1) ? AL1 : AL0;
        // in-stage ks2/ks3 weight loads (covered by ks0/ks1 MFMAs)
        const bfrag* wbase = wt1 + (wb + c * 4) * 128 + lane;
        bfrag c2h = wbase[256], c2l = wbase[320];
        bfrag c3h = wbase[384], c3l = wbase[448];
        #pragma unroll
        for (int ks = 0; ks < 4; ks++) {
            bfrag bh = (ks == 0) ? Bd[c & 1][0] : (ks == 1) ? Bd[c & 1][1]
                      : (ks == 2) ? c2h : c3h;
            bfrag bl = (ks == 0) ? Bd[c & 1][2] : (ks == 1) ? Bd[c & 1][3]
                      : (ks == 2) ? c2l : c3l;
            int kl = ks * 32 + quad * 8;
            bfrag ah0 = *(const bfrag*)&WAH[lane15][kl];
            bfrag ah1 = *(const bfrag*)&WAH[16 + lane15][kl];
            bfrag al0 = *(const bfrag*)&WAL[lane15][kl];
            bfrag al1 = *(const bfrag*)&WAL[16 + lane15][kl];
            aA0 = MFMA(ah0, bh, aA0);
            aB0 = MFMA(ah0, bl, aB0);
            aB0 = MFMA(al0, bh, aB0);
            aA1 = MFMA(ah1, bh, aA1);
            aB1 = MFMA(ah1, bl, aB1);
            aB1 = MFMA(al1, bh, aB1);
            if (ks == 1) {   // cross-barrier prefetch: next stage ks0/ks1
                const bfrag* nb = (c < 5)
                    ? wt1 + (wb + (c + 1) * 4) * 128 + lane
                    : wtr + ((size_t)(e * 4 + 0) * 8 + w) * 4 * 128 + lane;
                Bd[(c + 1) & 1][0] = nb[0];   Bd[(c + 1) & 1][1] = nb[128];
                Bd[(c + 1) & 1][2] = nb[64];  Bd[(c + 1) & 1][3] = nb[192];
            }
        }
        if (c < 5) {
            // write chunk c+1 into the other buffer
            arr136 NH = (c & 1) ? AH0 : AH1;
            arr136 NL = (c & 1) ? AL0 : AL1;
            float xv[8] = {p0.x, p0.y, p0.z, p0.w, p1.x, p1.y, p1.z, p1.w};
            unsigned short h8[8], l8[8];
            #pragma unroll
            for (int j = 0; j < 8; j++) split_bf16(fmaxf(xv[j], 0.f), h8[j], l8[j]);
            *(bfrag*)&NH[srow][scol] = *(bfrag*)h8;
            *(bfrag*)&NL[srow][scol] = *(bfrag*)l8;
            if (c < 4) {   // issue chunk c+2 loads
                const float* src = (c + 2 < 3) ? s : si;
                int kb0 = ((c + 2 < 3) ? (c + 2) : (c - 1)) * KC;
                p0 = *(const float4*)(src + rowoff + kb0);
                p1 = *(const float4*)(src + rowoff + kb0 + 4);
            }
        }
        BAR();
    }

    // ---- residual blocks: 4 GEMMs, one barrier each ----
    f32x4 h0 = aA0 + aB0;
    f32x4 h1 = aA1 + aB1;
    {   // write g0 A-data (relu(h) split) into buf0 — happens before this
        // point? No: chunk5 wrote nothing; do it here, then the loop's BAR
        // pattern is write->BAR->read.  (chunk5's BAR already passed; buf0's
        // last readers were chunk4, long done.)
        f32x4 cur[2] = {h0, h1};
        #pragma unroll
        for (int mt = 0; mt < 2; mt++) {
            #pragma unroll
            for (int rr = 0; rr < 4; rr++) {
                unsigned short hh, ll;
                split_bf16(fmaxf(cur[mt][rr], 0.f), hh, ll);
                AH0[mt * 16 + quad * 4 + rr][nc] = hh;
                AL0[mt * 16 + quad * 4 + rr][nc] = ll;
            }
        }
    }
    BAR();

    #pragma unroll
    for (int g = 0; g < 4; g++) {
        arr136 WAH = (g & 1) ? AH1 : AH0;
        arr136 WAL = (g & 1) ? AL1 : AL0;
        const bfrag* wbase = wtr + ((size_t)(e * 4 + g) * 8 + w) * 4 * 128 + lane;
        bfrag c2h = wbase[256], c2l = wbase[320];
        bfrag c3h = wbase[384], c3l = wbase[448];
        float bv = (g & 1) ? ((g >> 1) ? bvb2b : bvb2a)
                           : ((g >> 1) ? bvb1b : bvb1a);
        f32x4 rA0 = (f32x4){bv, bv, bv, bv}, rA1 = rA0;
        f32x4 rB0 = (f32x4){0.f, 0.f, 0.f, 0.f}, rB1 = rB0;
        #pragma unroll
        for (int ks = 0; ks < 4; ks++) {
            bfrag bh = (ks == 0) ? Bd[g & 1][0] : (ks == 1) ? Bd[g & 1][1]
                      : (ks == 2) ? c2h : c3h;
            bfrag bl = (ks == 0) ? Bd[g & 1][2] : (ks == 1) ? Bd[g & 1][3]
                      : (ks == 2) ? c2l : c3l;
            int kl = ks * 32 + quad * 8;
            bfrag ah0 = *(const bfrag*)&WAH[lane15][kl];
            bfrag ah1 = *(const bfrag*)&WAH[16 + lane15][kl];
            bfrag al0 = *(const bfrag*)&WAL[lane15][kl];
            bfrag al1 = *(const bfrag*)&WAL[16 + lane15][kl];
            rA0 = MFMA(ah0, bh, rA0);
            rB0 = MFMA(ah0, bl, rB0);
            rB0 = MFMA(al0, bh, rB0);
            rA1 = MFMA(ah1, bh, rA1);
            rB1 = MFMA(ah1, bl, rB1);
            rB1 = MFMA(al1, bh, rB1);
            if (ks == 1 && g < 3) {
                const bfrag* nb = wtr + ((size_t)(e * 4 + g + 1) * 8 + w) * 4 * 128 + lane;
                Bd[(g + 1) & 1][0] = nb[0];   Bd[(g + 1) & 1][1] = nb[128];
                Bd[(g + 1) & 1][2] = nb[64];  Bd[(g + 1) & 1][3] = nb[192];
            }
        }
        f32x4 r0 = rA0 + rB0, r1 = rA1 + rB1;
        if (g & 1) { h0 += r0; h1 += r1; }
        if (g < 3) {
            f32x4 cur0 = (g & 1) ? h0 : r0;
            f32x4 cur1 = (g & 1) ? h1 : r1;
            arr136 NH = (g & 1) ? AH0 : AH1;
            arr136 NL = (g & 1) ? AL0 : AL1;
            #pragma unroll
            for (int rr = 0; rr < 4; rr++) {
                unsigned short hh, ll;
                split_bf16(fmaxf(cur0[rr], 0.f), hh, ll);
                NH[quad * 4 + rr][nc] = hh;
                NL[quad * 4 + rr][nc] = ll;
                split_bf16(fmaxf(cur1[rr], 0.f), hh, ll);
                NH[16 + quad * 4 + rr][nc] = hh;
                NL[16 + quad * 4 + rr][nc] = ll;
            }
            BAR();
        } else {
            // epilogue staging: relu(h) fp32 -> Hf (buf0 region; free)
            #pragma unroll
            for (int rr = 0; rr < 4; rr++) {
                Hf[quad * 4 + rr][nc]      = fmaxf(h0[rr], 0.f);
                Hf[16 + quad * 4 + rr][nc] = fmaxf(h1[rr], 0.f);
            }
            BAR();
        }
    }

    // ---- out = relu(h) @ Wout + b_out (128 -> 14), 4-way partials ----
    const float* WoutE = Wout + (size_t)e * CH * (NANG * 2);
    const float* boutE = b_out + (size_t)e * (NANG * 2);
    for (int idx = t; idx < n * (NANG * 2); idx += TPB_MAIN) {
        int i = idx / (NANG * 2);
        int o = idx - i * (NANG * 2);
        float v0 = boutE[o], v1 = 0.f, v2 = 0.f, v3 = 0.f;
        #pragma unroll 4
        for (int k = 0; k < CH; k += 4) {
            v0 = fmaf(Hf[i][k],     WoutE[(size_t)k * (NANG * 2) + o],       v0);
            v1 = fmaf(Hf[i][k + 1], WoutE[(size_t)(k + 1) * (NANG * 2) + o], v1);
            v2 = fmaf(Hf[i][k + 2], WoutE[(size_t)(k + 2) * (NANG * 2) + o], v2);
            v3 = fmaf(Hf[i][k + 3], WoutE[(size_t)(k + 3) * (NANG * 2) + o], v3);
        }
        Of[i][o] = (v0 + v1) + (v2 + v3);
    }
    BAR();

    // ---- pair-normalize and store ----
    for (int idx = t; idx < n * NANG; idx += TPB_MAIN) {
        int i = idx / NANG;
        int a = idx - i * NANG;
        float x = Of[i][2 * a];
        float y = Of[i][2 * a + 1];
        float nr = fmaxf(sqrtf(x * x + y * y), 1e-12f);
        size_t base = (size_t)ptok[i] * (NANG * 2) + 2 * a;
        out[base]     = x / nr;
        out[base + 1] = y / nr;
    }
}

extern "C" void kernel_launch(void* const* d_in, const int* in_sizes, int n_in,
                              void* d_out, int out_size, void* d_ws, size_t ws_size,
                              hipStream_t stream) {
    const float* s       = (const float*)d_in[0];
    const float* s_init  = (const float*)d_in[1];
    const int*   aatype  = (const int*)d_in[2];
    const float* Win     = (const float*)d_in[3];
    const float* b_in    = (const float*)d_in[4];
    const float* Winit   = (const float*)d_in[5];
    const float* b_init2 = (const float*)d_in[6];
    const float* Wb1     = (const float*)d_in[7];
    const float* bb1     = (const float*)d_in[8];
    const float* Wb2     = (const float*)d_in[9];
    const float* bb2     = (const float*)d_in[10];
    const float* Wout    = (const float*)d_in[11];
    const float* b_out   = (const float*)d_in[12];
    int* wsI = (int*)d_ws;
    unsigned short* wt = (unsigned short*)d_ws;
    float* out = (float*)d_out;

    hipLaunchKernelGGL(prep1, dim3(1664), dim3(256), 0, stream,
                       Win, Winit, Wb1, Wb2, aatype, wsI, wt);
    hipLaunchKernelGGL(angle_main, dim3(MAX_TILES), dim3(TPB_MAIN), 0, stream,
                       s, s_init, b_in, b_init2, bb1, bb2, Wout, b_out,
                       aatype, wsI, wt, out);
}

// Round 4
// 159.398 us; speedup vs baseline: 1.0102x; 1.0102x over previous
//
#include <hip/hip_runtime.h>
#include <math.h>

#define E_TYPES 20
#define NBLK 2
#define NANG 7
#define CS 384
#define CH 128
#define N_TOK (8 * 2048)
#define TOK 16
#define TPB 256
#define TPB_MAIN 512
#define KC 128
#define MAX_TILES (N_TOK / TOK + E_TYPES)   // 1044
#define NPREP 64

// ---- workspace: int control region ----
#define HIST_OFF 0           // 64 x 20 per-block histograms

// ---- workspace: fragment-packed split-bf16 weights (bytes) ----
// 1KB block = 64 lanes x 16B; element (n,k): lane = (n&15)|((k>>3&3)<<4), j=k&7
#define WT1_OFF (256 * 1024)                       // phase-1 concat [768x128] per e
#define WT1_SZ  (20 * 8 * 24 * 2048)               // e x nt(8) x kb(24) x (hi1KB+lo1KB)
#define WTR_OFF (WT1_OFF + WT1_SZ)                 // residual: e x m4(4) x nt(8) x kb(4)
// total end ~13.4 MB

typedef __attribute__((ext_vector_type(8))) short bfrag;
typedef __attribute__((ext_vector_type(4))) float f32x4;
typedef unsigned short (*arr136)[136];

__device__ __forceinline__ void split_bf16(float x, unsigned short& h, unsigned short& l) {
    unsigned int u = __float_as_uint(x);
    unsigned int hb = (u + 0x7FFFu + ((u >> 16) & 1u)) & 0xFFFF0000u;
    h = (unsigned short)(hb >> 16);
    float r = x - __uint_as_float(hb);
    unsigned int v = __float_as_uint(r);
    l = (unsigned short)((v + 0x7FFFu + ((v >> 16) & 1u)) >> 16);
}

// prep1: blocks [0,1600) convert weights to fragment-packed split-bf16;
// blocks [1600,1664) build the per-block token histogram.
__global__ void prep1(const float* __restrict__ Win, const float* __restrict__ Winit,
                      const float* __restrict__ Wb1, const float* __restrict__ Wb2,
                      const int* __restrict__ aatype, int* __restrict__ wsI,
                      unsigned short* __restrict__ wt) {
    __shared__ int lh[E_TYPES];
    int bid = blockIdx.x;
    int t = threadIdx.x;
    if (bid >= 1600) {   // histogram part
        int b2 = bid - 1600;
        if (t < E_TYPES) lh[t] = 0;
        __syncthreads();
        int idx = b2 * 256 + t;
        if (idx < N_TOK) atomicAdd(&lh[aatype[idx]], 1);
        __syncthreads();
        if (t < E_TYPES) wsI[HIST_OFF + b2 * E_TYPES + t] = lh[t];
        return;
    }
    int gid = bid * 256 + t;
    unsigned short h[8], l[8];
    if (gid < 245760) {          // phase-1 weights: 20*8*24 blocks x 64 lanes
        int lane = gid & 63;
        int bi = gid >> 6;
        int kb = bi % 24;
        int r = bi / 24;
        int nt = r & 7, e = r >> 3;
        int n = nt * 16 + (lane & 15);
        int k0 = kb * 32 + (lane >> 4) * 8;
        #pragma unroll
        for (int j = 0; j < 8; j++) {
            int k = k0 + j;
            float x = (k < CS) ? Win[((size_t)e * CS + k) * CH + n]
                               : Winit[((size_t)e * CS + (k - CS)) * CH + n];
            split_bf16(x, h[j], l[j]);
        }
        unsigned short* dst = wt + (WT1_OFF / 2) + (size_t)bi * 1024 + lane * 8;
        *(bfrag*)dst = *(bfrag*)h;
        *(bfrag*)(dst + 512) = *(bfrag*)l;
    } else {                     // residual weights: 20*4*8*4 blocks x 64 lanes
        gid -= 245760;
        int lane = gid & 63;
        int bi = gid >> 6;       // 0..2559
        int kb = bi & 3;
        int nt = (bi >> 2) & 7;
        int m4 = (bi >> 5) & 3;
        int e = bi >> 7;
        int b = m4 >> 1;
        const float* W = (m4 & 1) ? Wb2 : Wb1;
        int n = nt * 16 + (lane & 15);
        int k0 = kb * 32 + (lane >> 4) * 8;
        #pragma unroll
        for (int j = 0; j < 8; j++) {
            int k = k0 + j;
            float x = W[(((size_t)e * NBLK + b) * CH + k) * CH + n];
            split_bf16(x, h[j], l[j]);
        }
        unsigned short* dst = wt + (WTR_OFF / 2) + (size_t)bi * 1024 + lane * 8;
        *(bfrag*)dst = *(bfrag*)h;
        *(bfrag*)(dst + 512) = *(bfrag*)l;
    }
}

#define MFMA(a, b, c) __builtin_amdgcn_mfma_f32_16x16x32_bf16((a), (b), (c), 0, 0, 0)

// TOK=16: 1044 blocks -> ~4 independent blocks/CU (the untested lever —
// waves within a block are barrier-locked; only separate blocks can
// interleave stage-stalls). 8 waves, wave w owns N-tile w, one 16-row
// M-tile. Body is the round-2 structure (best known): __syncthreads,
// double-buffered LDS, ks0/ks1 register prefetch, XCD-chunked swizzle.
__global__ __launch_bounds__(TPB_MAIN)
void angle_main(const float* __restrict__ s, const float* __restrict__ si,
                const float* __restrict__ b_in, const float* __restrict__ b_init2,
                const float* __restrict__ bb1, const float* __restrict__ bb2,
                const float* __restrict__ Wout, const float* __restrict__ b_out,
                const int* __restrict__ aatype,
                const int* __restrict__ wsI, const unsigned short* __restrict__ wt,
                float* __restrict__ out)
{
    // LDS pool: two (Ah,Al) buffers of [16][136] u16; epilogue Hf/Of overlap.
    #define BUFSZ 8704
    __shared__ __align__(16) char pool[2 * BUFSZ];
    __shared__ int ptok[TOK];
    __shared__ int cntS[E_TYPES];

    arr136 AH0 = (arr136)(pool);
    arr136 AL0 = (arr136)(pool + 4352);
    arr136 AH1 = (arr136)(pool + BUFSZ);
    arr136 AL1 = (arr136)(pool + BUFSZ + 4352);
    float (*Hf)[132] = (float (*)[132])(pool);            // 16*132*4 = 8448 <= BUFSZ
    float (*Of)[16]  = (float (*)[16])(pool + BUFSZ);     // 1KB

    int t = threadIdx.x;
    int w = t >> 6, lane = t & 63;
    int lane15 = lane & 15, quad = lane >> 4;

    // XCD-chunked bijective swizzle (e-sorted tiles -> per-XCD L2 residency).
    int bid = blockIdx.x;
    const int q = MAX_TILES >> 3, r = MAX_TILES & 7;   // 130, 4
    int xcd = bid & 7, sub = bid >> 3;
    int tile = (xcd < r ? xcd * (q + 1) : r * (q + 1) + (xcd - r) * q) + sub;

    // wave0: per-type totals from the 64x20 chunk histograms
    if (w == 0 && lane < E_TYPES) {
        int c = 0;
        #pragma unroll
        for (int b = 0; b < NPREP; b++) c += wsI[HIST_OFF + b * E_TYPES + lane];
        cntS[lane] = c;
    }
    __syncthreads();

    int pos = tile * TOK;
    int e = -1, poff_e = 0;
    {
        int accT = 0;
        #pragma unroll
        for (int ee = 0; ee < E_TYPES; ee++) {
            int pad = (cntS[ee] + TOK - 1) & ~(TOK - 1);
            if (e < 0 && pos < accT + pad) { e = ee; poff_e = accT; }
            accT += pad;
        }
        if (pos >= accT) return;     // uniform exit (all waves agree)
    }
    int pos_in = pos - poff_e;
    int n = cntS[e] - pos_in; if (n > TOK) n = TOK;

    int nc = w * 16 + lane15;
    const bfrag* wt1 = (const bfrag*)((const char*)wt + WT1_OFF);
    const bfrag* wtr = (const bfrag*)((const char*)wt + WTR_OFF);
    size_t wb = (size_t)(e * 8 + w) * 24;

    // Early issue: chunk-0 ks0/ks1 weight fragments + all bias values.
    bfrag Bd[2][4];
    {
        const bfrag* nb = wt1 + wb * 128 + lane;
        Bd[0][0] = nb[0];   Bd[0][1] = nb[128];
        Bd[0][2] = nb[64];  Bd[0][3] = nb[192];
    }
    float bv_in  = b_in[e * CH + nc] + b_init2[e * CH + nc];
    float bvb1a = bb1[(e * NBLK + 0) * CH + nc];
    float bvb1b = bb1[(e * NBLK + 1) * CH + nc];
    float bvb2a = bb2[(e * NBLK + 0) * CH + nc];
    float bvb2b = bb2[(e * NBLK + 1) * CH + nc];

    // wave0: rank-scan aatype -> ptok (overlaps other waves' prefetch)
    if (w == 0) {
        int hb = wsI[HIST_OFF + lane * E_TYPES + e];
        int inc = hb;
        #pragma unroll
        for (int d = 1; d < 64; d <<= 1) { int v = __shfl_up(inc, d); if (lane >= d) inc += v; }
        int pre = inc - hb;
        unsigned long long mle = __ballot(pre <= pos_in);
        int cb = 63 - __clzll(mle);
        int running = __shfl(pre, cb);
        int base = cb * 256;
        int lim = pos_in + n;
        while (running < lim && base < N_TOK) {
            const int4 a4 = *(const int4*)&aatype[base + lane * 4];
            int m0 = (a4.x == e), m1 = (a4.y == e), m2 = (a4.z == e), m3 = (a4.w == e);
            int c = m0 + m1 + m2 + m3;
            int incl = c;
            #pragma unroll
            for (int d = 1; d < 64; d <<= 1) { int v = __shfl_up(incl, d); if (lane >= d) incl += v; }
            int rk = running + incl - c;
            int tk = base + lane * 4;
            if (m0) { if (rk >= pos_in && rk < lim) ptok[rk - pos_in] = tk;     rk++; }
            if (m1) { if (rk >= pos_in && rk < lim) ptok[rk - pos_in] = tk + 1; rk++; }
            if (m2) { if (rk >= pos_in && rk < lim) ptok[rk - pos_in] = tk + 2; rk++; }
            if (m3) { if (rk >= pos_in && rk < lim) ptok[rk - pos_in] = tk + 3; rk++; }
            running += __shfl(incl, 63);
            base += 256;
        }
        int t0 = ptok[0];
        if (lane >= n && lane < TOK) ptok[lane] = t0;
    }
    __syncthreads();

    // ---- phase 1: h = [relu(s) relu(si)] @ [Win;Winit] + biases, K=768 ----
    // Staging: 32 threads/row x 4 floats; chunk c+1 prefetched into regs.
    int srow = t >> 5;
    int scol = (t & 31) * 4;
    size_t rowoff = (size_t)ptok[srow] * CS + scol;
    float4 p0 = *(const float4*)(s + rowoff);

    f32x4 aA = (f32x4){bv_in, bv_in, bv_in, bv_in};
    f32x4 aB = (f32x4){0.f, 0.f, 0.f, 0.f};

    #pragma unroll
    for (int c = 0; c < 6; c++) {
        arr136 WAH = (c & 1) ? AH1 : AH0;
        arr136 WAL = (c & 1) ? AL1 : AL0;
        {   // write the prefetched chunk (relu + split) to LDS
            ushort4 hv, lv;
            split_bf16(fmaxf(p0.x, 0.f), hv.x, lv.x);
            split_bf16(fmaxf(p0.y, 0.f), hv.y, lv.y);
            split_bf16(fmaxf(p0.z, 0.f), hv.z, lv.z);
            split_bf16(fmaxf(p0.w, 0.f), hv.w, lv.w);
            *(ushort4*)&WAH[srow][scol] = hv;
            *(ushort4*)&WAL[srow][scol] = lv;
        }
        if (c < 5) {   // prefetch next chunk activations
            const float* src = (c + 1 < 3) ? s : si;
            int kb0 = ((c + 1 < 3) ? (c + 1) : (c - 2)) * KC;
            p0 = *(const float4*)(src + rowoff + kb0);
        }
        __syncthreads();
        // in-stage ks2/ks3 weight loads (covered by ks0/ks1 MFMAs)
        const bfrag* wbase = wt1 + (wb + c * 4) * 128 + lane;
        bfrag c2h = wbase[256], c2l = wbase[320];
        bfrag c3h = wbase[384], c3l = wbase[448];
        #pragma unroll
        for (int ks = 0; ks < 4; ks++) {
            bfrag bh = (ks == 0) ? Bd[c & 1][0] : (ks == 1) ? Bd[c & 1][1]
                      : (ks == 2) ? c2h : c3h;
            bfrag bl = (ks == 0) ? Bd[c & 1][2] : (ks == 1) ? Bd[c & 1][3]
                      : (ks == 2) ? c2l : c3l;
            int kl = ks * 32 + quad * 8;
            bfrag ah = *(const bfrag*)&WAH[lane15][kl];
            bfrag al = *(const bfrag*)&WAL[lane15][kl];
            aA = MFMA(ah, bh, aA);
            aB = MFMA(ah, bl, aB);
            aB = MFMA(al, bh, aB);
            if (ks == 1) {   // prefetch next stage's ks0/ks1
                const bfrag* nb = (c < 5)
                    ? wt1 + (wb + (c + 1) * 4) * 128 + lane
                    : wtr + ((size_t)(e * 4 + 0) * 8 + w) * 4 * 128 + lane;
                Bd[(c + 1) & 1][0] = nb[0];   Bd[(c + 1) & 1][1] = nb[128];
                Bd[(c + 1) & 1][2] = nb[64];  Bd[(c + 1) & 1][3] = nb[192];
            }
        }
        __syncthreads();
    }

    // ---- residual blocks: 4 GEMMs, one barrier each ----
    f32x4 h0 = aA + aB;
    {   // write g0 A-data (relu(h) split) into buf0
        #pragma unroll
        for (int rr = 0; rr < 4; rr++) {
            unsigned short hh, ll;
            split_bf16(fmaxf(h0[rr], 0.f), hh, ll);
            AH0[quad * 4 + rr][nc] = hh;
            AL0[quad * 4 + rr][nc] = ll;
        }
    }
    __syncthreads();

    #pragma unroll
    for (int g = 0; g < 4; g++) {
        arr136 WAH = (g & 1) ? AH1 : AH0;
        arr136 WAL = (g & 1) ? AL1 : AL0;
        const bfrag* wbase = wtr + ((size_t)(e * 4 + g) * 8 + w) * 4 * 128 + lane;
        bfrag c2h = wbase[256], c2l = wbase[320];
        bfrag c3h = wbase[384], c3l = wbase[448];
        float bv = (g & 1) ? ((g >> 1) ? bvb2b : bvb2a)
                           : ((g >> 1) ? bvb1b : bvb1a);
        f32x4 rA = (f32x4){bv, bv, bv, bv};
        f32x4 rB = (f32x4){0.f, 0.f, 0.f, 0.f};
        #pragma unroll
        for (int ks = 0; ks < 4; ks++) {
            bfrag bh = (ks == 0) ? Bd[g & 1][0] : (ks == 1) ? Bd[g & 1][1]
                      : (ks == 2) ? c2h : c3h;
            bfrag bl = (ks == 0) ? Bd[g & 1][2] : (ks == 1) ? Bd[g & 1][3]
                      : (ks == 2) ? c2l : c3l;
            int kl = ks * 32 + quad * 8;
            bfrag ah = *(const bfrag*)&WAH[lane15][kl];
            bfrag al = *(const bfrag*)&WAL[lane15][kl];
            rA = MFMA(ah, bh, rA);
            rB = MFMA(ah, bl, rB);
            rB = MFMA(al, bh, rB);
            if (ks == 1 && g < 3) {
                const bfrag* nb = wtr + ((size_t)(e * 4 + g + 1) * 8 + w) * 4 * 128 + lane;
                Bd[(g + 1) & 1][0] = nb[0];   Bd[(g + 1) & 1][1] = nb[128];
                Bd[(g + 1) & 1][2] = nb[64];  Bd[(g + 1) & 1][3] = nb[192];
            }
        }
        f32x4 r0 = rA + rB;
        if (g & 1) h0 += r0;
        if (g < 3) {
            f32x4 cur = (g & 1) ? h0 : r0;
            arr136 NH = (g & 1) ? AH0 : AH1;
            arr136 NL = (g & 1) ? AL0 : AL1;
            #pragma unroll
            for (int rr = 0; rr < 4; rr++) {
                unsigned short hh, ll;
                split_bf16(fmaxf(cur[rr], 0.f), hh, ll);
                NH[quad * 4 + rr][nc] = hh;
                NL[quad * 4 + rr][nc] = ll;
            }
            __syncthreads();
        } else {
            // epilogue staging: relu(h) fp32 -> Hf (buf0 region; g2 readers done)
            #pragma unroll
            for (int rr = 0; rr < 4; rr++)
                Hf[quad * 4 + rr][nc] = fmaxf(h0[rr], 0.f);
            __syncthreads();
        }
    }

    // ---- out = relu(h) @ Wout + b_out (128 -> 14), 4-way partials ----
    const float* WoutE = Wout + (size_t)e * CH * (NANG * 2);
    const float* boutE = b_out + (size_t)e * (NANG * 2);
    for (int idx = t; idx < n * (NANG * 2); idx += TPB_MAIN) {
        int i = idx / (NANG * 2);
        int o = idx - i * (NANG * 2);
        float v0 = boutE[o], v1 = 0.f, v2 = 0.f, v3 = 0.f;
        #pragma unroll 4
        for (int k = 0; k < CH; k += 4) {
            v0 = fmaf(Hf[i][k],     WoutE[(size_t)k * (NANG * 2) + o],       v0);
            v1 = fmaf(Hf[i][k + 1], WoutE[(size_t)(k + 1) * (NANG * 2) + o], v1);
            v2 = fmaf(Hf[i][k + 2], WoutE[(size_t)(k + 2) * (NANG * 2) + o], v2);
            v3 = fmaf(Hf[i][k + 3], WoutE[(size_t)(k + 3) * (NANG * 2) + o], v3);
        }
        Of[i][o] = (v0 + v1) + (v2 + v3);
    }
    __syncthreads();

    // ---- pair-normalize and store ----
    for (int idx = t; idx < n * NANG; idx += TPB_MAIN) {
        int i = idx / NANG;
        int a = idx - i * NANG;
        float x = Of[i][2 * a];
        float y = Of[i][2 * a + 1];
        float nr = fmaxf(sqrtf(x * x + y * y), 1e-12f);
        size_t base = (size_t)ptok[i] * (NANG * 2) + 2 * a;
        out[base]     = x / nr;
        out[base + 1] = y / nr;
    }
}

extern "C" void kernel_launch(void* const* d_in, const int* in_sizes, int n_in,
                              void* d_out, int out_size, void* d_ws, size_t ws_size,
                              hipStream_t stream) {
    const float* s       = (const float*)d_in[0];
    const float* s_init  = (const float*)d_in[1];
    const int*   aatype  = (const int*)d_in[2];
    const float* Win     = (const float*)d_in[3];
    const float* b_in    = (const float*)d_in[4];
    const float* Winit   = (const float*)d_in[5];
    const float* b_init2 = (const float*)d_in[6];
    const float* Wb1     = (const float*)d_in[7];
    const float* bb1     = (const float*)d_in[8];
    const float* Wb2     = (const float*)d_in[9];
    const float* bb2     = (const float*)d_in[10];
    const float* Wout    = (const float*)d_in[11];
    const float* b_out   = (const float*)d_in[12];
    int* wsI = (int*)d_ws;
    unsigned short* wt = (unsigned short*)d_ws;
    float* out = (float*)d_out;

    hipLaunchKernelGGL(prep1, dim3(1664), dim3(256), 0, stream,
                       Win, Winit, Wb1, Wb2, aatype, wsI, wt);
    hipLaunchKernelGGL(angle_main, dim3(MAX_TILES), dim3(TPB_MAIN), 0, stream,
                       s, s_init, b_in, b_init2, bb1, bb2, Wout, b_out,
                       aatype, wsI, wt, out);
}